// Round 18
// baseline (3276.558 us; speedup 1.0000x reference)
//
#include <hip/hip_runtime.h>
#include <math.h>

// LSTM: I=5, H=64, L=3, O=1, B=1024, T=256, fp32 in/out.
// Round-21: layer-per-block pipeline with global h relay (break the lockstep).
// r20 POST-MORTEM (198.6us): issue cuts exhausted (-2.3%); pace is lockstep
// phase-serialization: 12 waves share ONE barrier -> MFMA phase and trans
// phase never overlap across waves (+~310cy barrier). r16/r17 proved
// intra-block fixes fail. THIS ROUND: 3-layer block split into 3 independent
// 4-wave blocks (grid 768 = 3 layers x 256 chunks). ~3 blocks/CU barrier
// INDEPENDENTLY -> HW scheduler interleaves their phases (the TLP that
// VGPR-quantum blocked at 12-wave granularity works at 4-wave granularity:
// 3 blocks/CU x 4 waves = 12 waves/CU, same occupancy, decoupled barriers).
// Inter-layer h: FULLY-BUFFERED global relay in workspace (67MB, no ring,
// no back-pressure -> no overwrite hazard, producers never wait) + monotonic
// agent-scope flags. Producer (g<2): every 2 steps vmcnt(0)+barrier then
// tid0 release-store flag=t (release's L2-writeback covers the whole
// block's writes: 4 waves share one CU=one XCD). Consumer (g>0): cached
// `seen` + acquire-poll (s_sleep backoff), prefetch h_below(t+1) at step-t
// head -> global latency hides under the step. Deadlock-safe by capacity:
// 768 blocks x 4 waves @ ~100 VGPR -> >=3 blocks/CU -> all resident.
// FALLBACK: ws_size < 68MB -> launch the r20 kernel (kept verbatim below).
// Kept math (bit-identical to r20): hi-only h (RNE), x hi-only, native
// __expf, cvt_pk publish, exec-masked frag loads, row-scatter combine=1j,
// bias as C-operand, rcp-merged i*g, fp32 h2f sidecar FC.
// Layouts (r8 hw-verified): C/D col=lane&15,row=(lane>>4)*4+reg;
// A row=lane&15, k=(lane>>4)*8+j.
// DO NOT set launch_bounds min-waves > 2 (r5/r18: allocator spills).

typedef __attribute__((ext_vector_type(8))) short bf16x8;
typedef __attribute__((ext_vector_type(4))) float f32x4;

constexpr int Hh  = 64;
constexpr int Tt  = 256;
constexpr int In  = 5;
constexpr int TBr = 4;     // batch rows per chunk (tile rows 0,4,8,12)
constexpr int NCH = 256;   // chunks (B/TBr)

// ---- r20 fallback kernel geometry ----
constexpr int NB  = 256;
constexpr int NT  = 768;
constexpr int RB_ = 144;    // row stride bytes (72 shorts)
constexpr int LB  = 2304;   // layer stride (16 rows * 144)
constexpr int PB  = 8192;   // fallback parity stride (pow2 pad)

// ---- pipe kernel geometry ----
constexpr int NTP = 256;    // 4 waves
constexpr int PBP = 2304;   // parity stride bytes (16 rows * 144, single layer)
// workspace: [flags 4096B][relay: 2 boundaries x NCH x Tt x 4b x 64u x 2B]
constexpr size_t RELAY_OFF  = 4096;
constexpr size_t RELAY_SZ   = (size_t)2 * NCH * Tt * TBr * Hh * 2;
constexpr size_t WS_NEED    = RELAY_OFF + RELAY_SZ;

__device__ __forceinline__ float tanhc(float x) {
    return fmaf(2.0f, __builtin_amdgcn_rcpf(1.0f + __expf(-2.0f * x)), -1.0f);
}
__device__ __forceinline__ short f2bf_rne(float f) {
    union { float f; unsigned u; } v; v.f = f;
    unsigned r = (v.u + 0x7fffu + ((v.u >> 16) & 1u)) >> 16;
    return (short)r;
}
__device__ __forceinline__ bf16x8 ldwfrag(const float* __restrict__ W,
                                          int n, int stride, int k0, int kmax) {
    bf16x8 r;
    #pragma unroll
    for (int j = 0; j < 8; ++j) {
        int k = k0 + j;
        float f = (k < kmax) ? W[n * stride + k] : 0.0f;
        r[j] = f2bf_rne(f);
    }
    return r;
}

#define MF(A, B, C) __builtin_amdgcn_mfma_f32_16x16x32_bf16(A, B, C, 0, 0, 0)
#define LBAR() asm volatile("s_waitcnt lgkmcnt(0)\n\ts_barrier" ::: "memory")

// ============================ pipe kernel ============================
// One block = (layer g, chunk c). 4 waves x 16 units. Per-step 4-wave
// barrier protects the own-layer LDS parity pair. Below-layer input via
// global relay prefetch (no LDS, no intra-step dependency on other blocks).
#define PSTEP(T, RO, WR, C0, C1, N0, N1) do {                                \
    const int t_ = (T);                                                      \
    if (g > 0 && t_ + 1 < Tt) {    /* ensure + prefetch below(t+1) */        \
        if (seen < t_ + 1) {                                                 \
            do {                                                             \
                seen = __hip_atomic_load(fbelow, __ATOMIC_ACQUIRE,           \
                                         __HIP_MEMORY_SCOPE_AGENT);          \
                if (seen < t_ + 1) __builtin_amdgcn_s_sleep(2);              \
            } while (seen < t_ + 1);                                         \
        }                                                                    \
        if (lreal) {                                                         \
            N0 = *(const bf16x8*)(rlb + (size_t)(t_ + 1) * 512);             \
            N1 = *(const bf16x8*)(rlb + (size_t)(t_ + 1) * 512 + 64);        \
        }                                                                    \
    }                                                                        \
    if (lreal) {                   /* own h(t-1) frags from LDS */           \
        oh0 = *(const bf16x8*)(RO);                                          \
        oh1 = *(const bf16x8*)((RO) + 64);                                   \
    }                                                                        \
    f32x4 acc[4];                                                            \
    _Pragma("unroll")                                                        \
    for (int gi = 0; gi < 4; ++gi)                                           \
        acc[gi] = MF(oh0, WH[gi][0], bsv[gi]);   /* bias as C */             \
    _Pragma("unroll")                                                        \
    for (int gi = 0; gi < 4; ++gi)                                           \
        acc[gi] = MF(oh1, WH[gi][1], acc[gi]);                               \
    if (g == 0) {                  /* input: x(t), hi-only */                \
        _Pragma("unroll")                                                    \
        for (int gi = 0; gi < 4; ++gi)                                       \
            acc[gi] = MF(xhi, WI[gi][0], acc[gi]);                           \
        if (xmask && t_ + 1 < Tt) {                                          \
            _Pragma("unroll")                                                \
            for (int jj = 0; jj < In; ++jj)                                  \
                xr[jj] = x[xbase + (size_t)(t_ + 1) * In + jj];              \
            _Pragma("unroll")                                                \
            for (int jj = 0; jj < In; ++jj)                                  \
                xhi[jj] = f2bf_rne(xr[jj]);                                  \
        }                                                                    \
    } else {                       /* input: h_below(t), prefetched */       \
        _Pragma("unroll")                                                    \
        for (int gi = 0; gi < 4; ++gi)                                       \
            acc[gi] = MF(C0, WI[gi][0], acc[gi]);                            \
        _Pragma("unroll")                                                    \
        for (int gi = 0; gi < 4; ++gi)                                       \
            acc[gi] = MF(C1, WI[gi][1], acc[gi]);                            \
    }                                                                        \
    /* combine, j=0 only: output (b=kg, u=ub+col), all 64 lanes real */      \
    float ei = __expf(-acc[0][0]);                                           \
    float ef = __expf(-acc[1][0]);                                           \
    float eg = __expf(-2.0f * acc[2][0]);                                    \
    float eo = __expf(-acc[3][0]);                                           \
    float ig = (1.0f - eg) *                                                 \
               __builtin_amdgcn_rcpf((1.0f + ei) * (1.0f + eg));             \
    float fv = __builtin_amdgcn_rcpf(1.0f + ef);                             \
    float cn = fmaf(fv, c0, ig);                                             \
    c0 = cn;                                                                 \
    float ov = __builtin_amdgcn_rcpf(1.0f + eo);                             \
    float hn = ov * tanhc(cn);                                               \
    unsigned pk_;                                                            \
    asm("v_cvt_pk_bf16_f32 %0, %1, %2" : "=v"(pk_) : "v"(hn), "v"(hn));      \
    *(short*)(WR) = (short)pk_;                        /* own LDS */         \
    if (g < 2) *(short*)(wlb + (size_t)t_ * 512) = (short)pk_; /* relay */   \
    else       h2f[kg][ub + col] = hn;                 /* fp32 sidecar */    \
    if (g < 2 && (t_ & 1) == 1) {  /* flag step: drain + publish */          \
        asm volatile("s_waitcnt vmcnt(0) lgkmcnt(0)\n\ts_barrier":::"memory");\
        if (tid == 0)                                                        \
            __hip_atomic_store(fown, t_, __ATOMIC_RELEASE,                   \
                               __HIP_MEMORY_SCOPE_AGENT);                    \
    } else {                                                                 \
        LBAR();                                                              \
    }                                                                        \
} while (0)

__global__ __launch_bounds__(NTP, 2) void lstm3_pipe(
    const float* __restrict__ x,
    const float* __restrict__ w_ih0, const float* __restrict__ w_hh0,
    const float* __restrict__ b_ih0, const float* __restrict__ b_hh0,
    const float* __restrict__ w_ih1, const float* __restrict__ w_hh1,
    const float* __restrict__ b_ih1, const float* __restrict__ b_hh1,
    const float* __restrict__ w_ih2, const float* __restrict__ w_hh2,
    const float* __restrict__ b_ih2, const float* __restrict__ b_hh2,
    const float* __restrict__ w_fc,  const float* __restrict__ b_fc,
    float* __restrict__ out, char* __restrict__ ws)
{
    __shared__ short hb[2 * PBP / 2];   // [parity][16 rows][72] (4.6 KB)
    __shared__ float h2f[TBr][Hh];      // fp32 h2 sidecar (g==2)

    const int tid = threadIdx.x;
    const int l   = tid & 63;
    const int w4  = tid >> 6;        // wave 0..3 = unit slice
    const int g   = blockIdx.x % 3;  // layer (interleaved for dispatch spread)
    const int c   = blockIdx.x / 3;  // batch chunk
    const int ub  = w4 * 16;
    const int col = l & 15;
    const int kg  = l >> 4;
    const int b0  = c * TBr;
    const bool lreal = ((col & 3) == 0);

    // ---- zero LDS parities (h(t<0)=0) ----
    for (int i = tid; i < 2 * PBP / 4; i += NTP) ((int*)hb)[i] = 0;

    // ---- workspace: flags + relay ----
    int*  flags  = (int*)ws;
    int*  fown   = flags + g * NCH + c;                        // g<2
    int*  fbelow = flags + ((g > 0 ? g - 1 : 0)) * NCH + c;    // g>0
    char* relay  = ws + RELAY_OFF;
    // producer write base: lane (col,kg) owns (b=kg, u=ub+col)
    char* wlb = relay + ((size_t)(g * NCH + c) * Tt) * 512
              + kg * 128 + (ub + col) * 2;
    // consumer read base: lane (col,kg) reads A-frag row b=col>>2, k-slice kg
    const char* rlb = relay + ((size_t)((g > 0 ? g - 1 : 0) * NCH + c) * Tt) * 512
                    + (col >> 2) * 128 + kg * 16;

    // ---- per-layer weights ----
    const float* whh = (g == 0) ? w_hh0 : (g == 1) ? w_hh1 : w_hh2;
    const float* wih = (g == 0) ? w_ih0 : (g == 1) ? w_ih1 : w_ih2;
    const float* bih = (g == 0) ? b_ih0 : (g == 1) ? b_ih1 : b_ih2;
    const float* bhh = (g == 0) ? b_hh0 : (g == 1) ? b_hh1 : b_hh2;

    bf16x8 WH[4][2], WI[4][2];
    f32x4  bsv[4];
    #pragma unroll
    for (int gi = 0; gi < 4; ++gi) {
        int n = gi * 64 + ub + col;
        float bs_ = bih[n] + bhh[n];
        bsv[gi] = (f32x4){bs_, bs_, bs_, bs_};
        #pragma unroll
        for (int kt = 0; kt < 2; ++kt) {
            WH[gi][kt] = ldwfrag(whh, n, Hh, kt * 32 + kg * 8, Hh);
            if (g == 0) {
                WI[gi][kt] = (kt == 0) ? ldwfrag(wih, n, In, kg * 8, In)
                                       : ldwfrag(wih, n, In, 64, 0);
            } else {
                WI[gi][kt] = ldwfrag(wih, n, Hh, kt * 32 + kg * 8, Hh);
            }
        }
    }

    // ---- LDS base pointers (parity A reads p1/writes p0; B opposite) ----
    char* hbB = (char*)hb;
    const char* roB = hbB + col * RB_ + kg * 16;          // parity 0 read
    const char* roA = roB + PBP;                          // parity 1 read
    char* wrA = hbB + (kg * 4) * RB_ + (ub + col) * 2;    // parity 0 write
    char* wrB = wrA + PBP;                                // parity 1 write

    // ---- x boot (g==0) ----
    const bool xmask = (g == 0) && (kg == 0) && lreal;
    const size_t xbase = (size_t)(b0 + (col >> 2)) * Tt * In;
    float xr[5] = {0.f, 0.f, 0.f, 0.f, 0.f};
    bf16x8 xhi, oh0, oh1, ca0, ca1, cb0, cb1;
    #pragma unroll
    for (int j = 0; j < 8; ++j) {
        xhi[j] = 0; oh0[j] = 0; oh1[j] = 0;
        ca0[j] = 0; ca1[j] = 0; cb0[j] = 0; cb1[j] = 0;
    }
    if (xmask) {
        #pragma unroll
        for (int j = 0; j < In; ++j) xr[j] = x[xbase + j];
        #pragma unroll
        for (int j = 0; j < In; ++j) xhi[j] = f2bf_rne(xr[j]);
    }

    int   seen = -1;   // cached below-layer flag (g>0)
    float c0   = 0.f;  // cell state for (b=kg, u=ub+col)

    __syncthreads();   // LDS zero visible

    // ---- boot: consumer fetch h_below(0) ----
    if (g > 0) {
        do {
            seen = __hip_atomic_load(fbelow, __ATOMIC_ACQUIRE,
                                     __HIP_MEMORY_SCOPE_AGENT);
            if (seen < 0) __builtin_amdgcn_s_sleep(4);
        } while (seen < 0);
        if (lreal) {
            ca0 = *(const bf16x8*)(rlb);
            ca1 = *(const bf16x8*)(rlb + 64);
        }
    }

    // ---- main loop: 256 steps, 2x parity unroll ----
    #pragma unroll 1
    for (int t2 = 0; t2 < Tt; t2 += 2) {
        PSTEP(t2,     roA, wrA, ca0, ca1, cb0, cb1);  // read p1, write p0
        PSTEP(t2 + 1, roB, wrB, cb0, cb1, ca0, ca1);  // read p0, write p1
    }

    // ---- final FC (g==2) from the fp32 sidecar ----
    if (g == 2) {
        __syncthreads();
        if (tid < TBr) {
            const int b = tid;
            float accf = b_fc[0];
            #pragma unroll 1
            for (int u = 0; u < Hh; ++u)
                accf = fmaf(h2f[b][u], w_fc[u], accf);
            out[b0 + b] = accf;
        }
    }
}

// ============================ r20 fallback ============================
#define STEP(TI, RO, RBp, WR) do {                                           \
    const int ti_ = (TI);                                                    \
    const bool act_ = (wg == 0) ? (ti_ < Tt)                                 \
                    : (wg == 1) ? (ti_ >= 1 && ti_ <= Tt)                    \
                                : (ti_ >= 2);                                \
    if (act_) {                                                              \
        if (lreal) {                                                         \
            foh0 = *(const bf16x8*)(RO);                                     \
            foh1 = *(const bf16x8*)((RO) + 64);                              \
            if (wg > 0) {                                                    \
                fbh0 = *(const bf16x8*)(RBp);                                \
                fbh1 = *(const bf16x8*)((RBp) + 64);                         \
            }                                                                \
        }                                                                    \
        f32x4 acc[4];                                                        \
        _Pragma("unroll")                                                    \
        for (int gi = 0; gi < 4; ++gi)                                       \
            acc[gi] = MF(foh0, WH[gi][0], bsv[gi]);                          \
        _Pragma("unroll")                                                    \
        for (int gi = 0; gi < 4; ++gi)                                       \
            acc[gi] = MF(foh1, WH[gi][1], acc[gi]);                          \
        if (wg == 0) {                                                       \
            _Pragma("unroll")                                                \
            for (int gi = 0; gi < 4; ++gi)                                   \
                acc[gi] = MF(fxhi, WI[gi][0], acc[gi]);                      \
        } else {                                                             \
            _Pragma("unroll")                                                \
            for (int gi = 0; gi < 4; ++gi)                                   \
                acc[gi] = MF(fbh0, WI[gi][0], acc[gi]);                      \
            _Pragma("unroll")                                                \
            for (int gi = 0; gi < 4; ++gi)                                   \
                acc[gi] = MF(fbh1, WI[gi][1], acc[gi]);                      \
        }                                                                    \
        if (xmask && ti_ + 1 < Tt) {                                         \
            _Pragma("unroll")                                                \
            for (int jj = 0; jj < In; ++jj)                                  \
                xr[jj] = x[xbase + (size_t)(ti_ + 1) * In + jj];             \
            _Pragma("unroll")                                                \
            for (int jj = 0; jj < In; ++jj)                                  \
                fxhi[jj] = f2bf_rne(xr[jj]);                                 \
        }                                                                    \
        float ei = __expf(-acc[0][0]);                                       \
        float ef = __expf(-acc[1][0]);                                       \
        float eg = __expf(-2.0f * acc[2][0]);                                \
        float eo = __expf(-acc[3][0]);                                       \
        float ig = (1.0f - eg) *                                             \
                   __builtin_amdgcn_rcpf((1.0f + ei) * (1.0f + eg));         \
        float fv = __builtin_amdgcn_rcpf(1.0f + ef);                         \
        float cn = fmaf(fv, c0, ig);                                         \
        c0 = cn;                                                             \
        float ov = __builtin_amdgcn_rcpf(1.0f + eo);                         \
        float hn = ov * tanhc(cn);                                           \
        unsigned pk_;                                                        \
        asm("v_cvt_pk_bf16_f32 %0, %1, %2" : "=v"(pk_) : "v"(hn), "v"(hn));  \
        *(short*)(WR) = (short)pk_;                                          \
        if (wg == 2) h2f[kg][ub + col] = hn;                                 \
    }                                                                        \
    LBAR();                                                                  \
} while (0)

__global__ __launch_bounds__(NT, 2) void lstm3_mfma(
    const float* __restrict__ x,
    const float* __restrict__ w_ih0, const float* __restrict__ w_hh0,
    const float* __restrict__ b_ih0, const float* __restrict__ b_hh0,
    const float* __restrict__ w_ih1, const float* __restrict__ w_hh1,
    const float* __restrict__ b_ih1, const float* __restrict__ b_hh1,
    const float* __restrict__ w_ih2, const float* __restrict__ w_hh2,
    const float* __restrict__ b_ih2, const float* __restrict__ b_hh2,
    const float* __restrict__ w_fc,  const float* __restrict__ b_fc,
    float* __restrict__ out)
{
    __shared__ short hb[2][PB / 2];
    __shared__ float h2f[TBr][Hh];

    const int tid = threadIdx.x;
    const int l   = tid & 63;
    const int wid = tid >> 6;
    const int wg  = wid >> 2;
    const int w4  = wid & 3;
    const int ub  = w4 * 16;
    const int col = l & 15;
    const int kg  = l >> 4;
    const int b0  = blockIdx.x * TBr;
    const bool lreal = ((col & 3) == 0);

    for (int i = tid; i < PB * 2 / 4; i += NT) ((int*)hb)[i] = 0;

    const float* whh = (wg == 0) ? w_hh0 : (wg == 1) ? w_hh1 : w_hh2;
    const float* wih = (wg == 0) ? w_ih0 : (wg == 1) ? w_ih1 : w_ih2;
    const float* bih = (wg == 0) ? b_ih0 : (wg == 1) ? b_ih1 : b_ih2;
    const float* bhh = (wg == 0) ? b_hh0 : (wg == 1) ? b_hh1 : b_hh2;

    bf16x8 WH[4][2], WI[4][2];
    f32x4  bsv[4];
    #pragma unroll
    for (int gi = 0; gi < 4; ++gi) {
        int n = gi * 64 + ub + col;
        float bs_ = bih[n] + bhh[n];
        bsv[gi] = (f32x4){bs_, bs_, bs_, bs_};
        #pragma unroll
        for (int kt = 0; kt < 2; ++kt) {
            WH[gi][kt] = ldwfrag(whh, n, Hh, kt * 32 + kg * 8, Hh);
            if (wg == 0) {
                WI[gi][kt] = (kt == 0) ? ldwfrag(wih, n, In, kg * 8, In)
                                       : ldwfrag(wih, n, In, 64, 0);
            } else {
                WI[gi][kt] = ldwfrag(wih, n, Hh, kt * 32 + kg * 8, Hh);
            }
        }
    }

    char* hbB = (char*)hb;
    const int lbelow = (wg > 0) ? (wg - 1) : 0;
    const int lown   = (wg > 0) ? LB : 0;
    const char* rbB_ = hbB + lbelow * LB + col * RB_ + kg * 16;
    const char* rbA_ = rbB_ + PB;
    const char* roA  = rbA_ + lown;
    const char* roB  = rbB_ + lown;
    char* wrA = hbB + wg * LB + (kg * 4) * RB_ + (ub + col) * 2;
    char* wrB = wrA + PB;

    const bool xmask = (wg == 0) && (kg == 0) && lreal;
    const size_t xbase = (size_t)(b0 + (col >> 2)) * Tt * In;
    float xr[5] = {0.f, 0.f, 0.f, 0.f, 0.f};
    bf16x8 fxhi, foh0, foh1, fbh0, fbh1;
    #pragma unroll
    for (int j = 0; j < 8; ++j) {
        fxhi[j] = 0; foh0[j] = 0; foh1[j] = 0; fbh0[j] = 0; fbh1[j] = 0;
    }
    if (xmask) {
        #pragma unroll
        for (int j = 0; j < In; ++j) xr[j] = x[xbase + j];
        #pragma unroll
        for (int j = 0; j < In; ++j) fxhi[j] = f2bf_rne(xr[j]);
    }

    float c0 = 0.f;

    __syncthreads();

    #pragma unroll 1
    for (int t2 = 0; t2 < Tt + 2; t2 += 2) {
        STEP(t2,     roA, rbA_, wrA);
        STEP(t2 + 1, roB, rbB_, wrB);
    }

    if (tid < TBr) {
        const int b = tid;
        float accf = b_fc[0];
        #pragma unroll 1
        for (int u = 0; u < Hh; ++u)
            accf = fmaf(h2f[b][u], w_fc[u], accf);
        out[b0 + b] = accf;
    }
}

extern "C" void kernel_launch(void* const* d_in, const int* in_sizes, int n_in,
                              void* d_out, int out_size, void* d_ws, size_t ws_size,
                              hipStream_t stream) {
    const float* x     = (const float*)d_in[0];
    const float* w_ih0 = (const float*)d_in[1];
    const float* w_hh0 = (const float*)d_in[2];
    const float* b_ih0 = (const float*)d_in[3];
    const float* b_hh0 = (const float*)d_in[4];
    const float* w_ih1 = (const float*)d_in[5];
    const float* w_hh1 = (const float*)d_in[6];
    const float* b_ih1 = (const float*)d_in[7];
    const float* b_hh1 = (const float*)d_in[8];
    const float* w_ih2 = (const float*)d_in[9];
    const float* w_hh2 = (const float*)d_in[10];
    const float* b_ih2 = (const float*)d_in[11];
    const float* b_hh2 = (const float*)d_in[12];
    const float* w_fc  = (const float*)d_in[13];
    const float* b_fc  = (const float*)d_in[14];
    float* out = (float*)d_out;

    if (d_ws != nullptr && ws_size >= WS_NEED) {
        // flags := -1 (0xFF bytes); captured in the graph, replays each run
        hipMemsetAsync(d_ws, 0xFF, 2 * NCH * sizeof(int), stream);
        lstm3_pipe<<<3 * NCH, NTP, 0, stream>>>(x,
            w_ih0, w_hh0, b_ih0, b_hh0,
            w_ih1, w_hh1, b_ih1, b_hh1,
            w_ih2, w_hh2, b_ih2, b_hh2,
            w_fc, b_fc, out, (char*)d_ws);
    } else {
        lstm3_mfma<<<NB, NT, 0, stream>>>(x,
            w_ih0, w_hh0, b_ih0, b_hh0,
            w_ih1, w_hh1, b_ih1, b_hh1,
            w_ih2, w_hh2, b_ih2, b_hh2,
            w_fc, b_fc, out);
    }
}

// Round 19
// 257.461 us; speedup vs baseline: 12.7264x; 12.7264x over previous
//
#include <hip/hip_runtime.h>
#include <math.h>

// LSTM: I=5, H=64, L=3, O=1, B=1024, T=256, fp32 in/out.
// Round-22: REVERT to r20 (198.6us best) + split-accumulator MFMA chains.
// r21 POST-MORTEM: global-relay pipe = 3251us, MfmaUtil 2.3% -- per-step
// cross-XCD acquire/release round-trip + s_sleep parking dominates. The
// structural scan is COMPLETE and every alternative to lockstep lost:
//   lockstep(199) < stagger(236) < spin(344) < seq-2x(405) < relay(3251)
// Remaining refinement: r20's per-gate MFMA chain is 3-4 dependent MFMAs
// (oh0->oh1->input). THIS ROUND splits the input GEMM into an independent
// acc2 chain (2-deep max), merged with 4 scalar adds (combine only reads
// the j=0 element). wg0's x-MFMAs (register-resident xhi) can now issue
// BEFORE the ds_read resolves. +16 VGPR (~88 total, <128 quantum), saves
// ~70-200cy/interval of MFMA serial latency.
// If flat (>=195us dispatch): structure is at its measured floor ->
// declare ROOFLINE next round with this kernel in place.
// Kept from r20: TBr=4/NB=256, single lgkmcnt-only barrier/step, native
// __expf, cvt_pk publish, exec-masked frag loads, hi-only h (RNE) + x
// hi-only, fp32 h2f sidecar FC, row-scatter combine=1j, bias as C-operand,
// rcp-merged i*g (safe: |preact|<=~12), fused imm-offset LDS +
// loop-invariant pointers (incl kg*16 k-slice), 2x parity unroll,
// persistent frags, no setprio.
// Layouts (r8 hw-verified): C/D col=lane&15,row=(lane>>4)*4+reg;
// A row=lane&15, k=(lane>>4)*8+j.
// DO NOT set launch_bounds min-waves > 2 (r5/r18: allocator spills).

typedef __attribute__((ext_vector_type(8))) short bf16x8;
typedef __attribute__((ext_vector_type(4))) float f32x4;

constexpr int Hh  = 64;
constexpr int Tt  = 256;
constexpr int In  = 5;
constexpr int TBr = 4;     // REAL batch rows per block (tile rows 0,4,8,12)
constexpr int NB  = 256;   // blocks (NB*TBr = 1024 = B); 1 block/CU
constexpr int NT  = 768;   // threads (12 waves)

// LDS geometry (bytes), hi-only: one array, immediate-offset addressable.
constexpr int RB_ = 144;    // row stride (72 shorts, bank-spread pad)
constexpr int LB  = 2304;   // layer stride (16 rows * 144)
constexpr int PB  = 8192;   // parity stride (6912 used, padded to pow2)

__device__ __forceinline__ float tanhc(float x) {
    // tanh(x) = 2*sigmoid(2x) - 1; saturates correctly, NaN-free
    return fmaf(2.0f, __builtin_amdgcn_rcpf(1.0f + __expf(-2.0f * x)), -1.0f);
}

// fp32 -> bf16 round-to-nearest-even (weight/x load path)
__device__ __forceinline__ short f2bf_rne(float f) {
    union { float f; unsigned u; } v; v.f = f;
    unsigned r = (v.u + 0x7fffu + ((v.u >> 16) & 1u)) >> 16;
    return (short)r;
}

__device__ __forceinline__ bf16x8 ldwfrag(const float* __restrict__ W,
                                          int n, int stride, int k0, int kmax) {
    bf16x8 r;
    #pragma unroll
    for (int j = 0; j < 8; ++j) {
        int k = k0 + j;
        float f = (k < kmax) ? W[n * stride + k] : 0.0f;
        r[j] = f2bf_rne(f);
    }
    return r;
}

#define MF(A, B, C) __builtin_amdgcn_mfma_f32_16x16x32_bf16(A, B, C, 0, 0, 0)

// Barrier: drain LDS ops only (writes visible), skip vmcnt (x load stays in
// flight; compiler waits vmcnt at the use point).
#define LBAR() asm volatile("s_waitcnt lgkmcnt(0)\n\ts_barrier" ::: "memory")

// One pipelined timestep. RO: own-layer read base (this iter's read parity),
// RBp: below-layer read base, WR: write base (opposite parity).
#define STEP(TI, RO, RBp, WR) do {                                           \
    const int ti_ = (TI);                                                    \
    const bool act_ = (wg == 0) ? (ti_ < Tt)                                 \
                    : (wg == 1) ? (ti_ >= 1 && ti_ <= Tt)                    \
                                : (ti_ >= 2);                                \
    if (act_) {                                                              \
        f32x4 acc[4], acc2[4];                                               \
        if (wg == 0) {   /* x-chain first: no ds dependency, hides read */   \
            _Pragma("unroll")                                                \
            for (int gi = 0; gi < 4; ++gi)                                   \
                acc2[gi] = MF(xhi, WI[gi][0], z4);                           \
        }                                                                    \
        if (lreal) {   /* exec-masked frag loads: real rows only */          \
            oh0 = *(const bf16x8*)(RO);                                      \
            oh1 = *(const bf16x8*)((RO) + 64);                               \
            if (wg > 0) {                                                    \
                bh0 = *(const bf16x8*)(RBp);                                 \
                bh1 = *(const bf16x8*)((RBp) + 64);                          \
            }                                                                \
        }                                                                    \
        _Pragma("unroll")                                                    \
        for (int gi = 0; gi < 4; ++gi)                                       \
            acc[gi] = MF(oh0, WH[gi][0], bsv[gi]);   /* bias as C */         \
        if (wg > 0) {      /* independent below-input chain (2-deep) */      \
            _Pragma("unroll")                                                \
            for (int gi = 0; gi < 4; ++gi)                                   \
                acc2[gi] = MF(bh0, WI[gi][0], z4);                           \
        }                                                                    \
        _Pragma("unroll")                                                    \
        for (int gi = 0; gi < 4; ++gi)                                       \
            acc[gi] = MF(oh1, WH[gi][1], acc[gi]);                           \
        if (wg > 0) {                                                        \
            _Pragma("unroll")                                                \
            for (int gi = 0; gi < 4; ++gi)                                   \
                acc2[gi] = MF(bh1, WI[gi][1], acc2[gi]);                     \
        }                                                                    \
        if (xmask && ti_ + 1 < Tt) {  /* load + split x(t+1) off the head */ \
            _Pragma("unroll")                                                \
            for (int jj = 0; jj < In; ++jj)                                  \
                xr[jj] = x[xbase + (size_t)(ti_ + 1) * In + jj];             \
            _Pragma("unroll")                                                \
            for (int jj = 0; jj < In; ++jj)                                  \
                xhi[jj] = f2bf_rne(xr[jj]);                                  \
        }                                                                    \
        /* combine, j=0 only: output (b=kg, u=ub+col), all 64 lanes real */  \
        float gi_ = acc[0][0] + acc2[0][0];                                  \
        float gf_ = acc[1][0] + acc2[1][0];                                  \
        float gg_ = acc[2][0] + acc2[2][0];                                  \
        float go_ = acc[3][0] + acc2[3][0];                                  \
        float ei = __expf(-gi_);                                             \
        float ef = __expf(-gf_);                                             \
        float eg = __expf(-2.0f * gg_);                                      \
        float eo = __expf(-go_);                                             \
        float ig = (1.0f - eg) *                                             \
                   __builtin_amdgcn_rcpf((1.0f + ei) * (1.0f + eg));         \
        float fv = __builtin_amdgcn_rcpf(1.0f + ef);                         \
        float cn = fmaf(fv, c0, ig);                                         \
        c0 = cn;                                                             \
        float ov = __builtin_amdgcn_rcpf(1.0f + eo);                         \
        float hn = ov * tanhc(cn);                                           \
        unsigned pk_;                                                        \
        asm("v_cvt_pk_bf16_f32 %0, %1, %2" : "=v"(pk_) : "v"(hn), "v"(hn));  \
        *(short*)(WR) = (short)pk_;                                          \
        if (wg == 2) h2f[kg][ub + col] = hn;   /* fp32 sidecar for FC */     \
    }                                                                        \
    LBAR();                                                                  \
} while (0)

__global__ __launch_bounds__(NT, 2) void lstm3_mfma(
    const float* __restrict__ x,
    const float* __restrict__ w_ih0, const float* __restrict__ w_hh0,
    const float* __restrict__ b_ih0, const float* __restrict__ b_hh0,
    const float* __restrict__ w_ih1, const float* __restrict__ w_hh1,
    const float* __restrict__ b_ih1, const float* __restrict__ b_hh1,
    const float* __restrict__ w_ih2, const float* __restrict__ w_hh2,
    const float* __restrict__ b_ih2, const float* __restrict__ b_hh2,
    const float* __restrict__ w_fc,  const float* __restrict__ b_fc,
    float* __restrict__ out)
{
    // [parity PB | layer LB | row RB_] fused hi-only h buffer (16 KB)
    __shared__ short hb[2][PB / 2];
    __shared__ float h2f[TBr][Hh];      // fp32 h2 sidecar (1 KB)

    const int tid = threadIdx.x;
    const int l   = tid & 63;
    const int wid = tid >> 6;        // 0..11
    const int wg  = wid >> 2;        // layer group 0..2
    const int w4  = wid & 3;         // wave within layer
    const int ub  = w4 * 16;         // unit base
    const int col = l & 15;          // A-row / B-col index
    const int kg  = l >> 4;          // k-group 0..3
    const int b0  = blockIdx.x * TBr;
    const bool lreal = ((col & 3) == 0);   // lane's A-row is a real batch row
    const f32x4 z4 = (f32x4){0.f, 0.f, 0.f, 0.f};

    // ---- zero both parities (pipeline fill; dead rows stay 0) ----
    for (int i = tid; i < PB * 2 / 4; i += NT) ((int*)hb)[i] = 0;

    // ---- per-layer weight selection ----
    const float* whh = (wg == 0) ? w_hh0 : (wg == 1) ? w_hh1 : w_hh2;
    const float* wih = (wg == 0) ? w_ih0 : (wg == 1) ? w_ih1 : w_ih2;
    const float* bih = (wg == 0) ? b_ih0 : (wg == 1) ? b_ih1 : b_ih2;
    const float* bhh = (wg == 0) ? b_hh0 : (wg == 1) ? b_hh1 : b_hh2;

    // ---- weights -> register fragments (once); bias pre-splat as C ----
    bf16x8 WH[4][2], WI[4][2];
    f32x4  bsv[4];
    #pragma unroll
    for (int gi = 0; gi < 4; ++gi) {
        int n = gi * 64 + ub + col;
        float bs_ = bih[n] + bhh[n];
        bsv[gi] = (f32x4){bs_, bs_, bs_, bs_};
        #pragma unroll
        for (int kt = 0; kt < 2; ++kt) {
            WH[gi][kt] = ldwfrag(whh, n, Hh, kt * 32 + kg * 8, Hh);
            if (wg == 0) {
                WI[gi][kt] = (kt == 0) ? ldwfrag(wih, n, In, kg * 8, In)
                                       : ldwfrag(wih, n, In, 64, 0);
            } else {
                WI[gi][kt] = ldwfrag(wih, n, Hh, kt * 32 + kg * 8, Hh);
            }
        }
    }

    // ---- loop-invariant LDS base pointers (read incl. kg*16 k-slice!) ----
    char* hbB = (char*)hb;
    const int lbelow = (wg > 0) ? (wg - 1) : 0;
    const int lown   = (wg > 0) ? LB : 0;       // own = below + LB (wg0: +0)
    const char* rbB_ = hbB + lbelow * LB + col * RB_ + kg * 16;   // parity 0
    const char* rbA_ = rbB_ + PB;                                 // parity 1
    const char* roA  = rbA_ + lown;
    const char* roB  = rbB_ + lown;
    // write: real batch b=kg lives at tile row 4*kg (j=0 slot of kg)
    char* wrA = hbB + wg * LB + (kg * 4) * RB_ + (ub + col) * 2;  // parity 0
    char* wrB = wrA + PB;                                         // parity 1

    // ---- x prefetch: only lanes whose A-row is real (col%4==0) ----
    const bool xmask = (wg == 0) && (kg == 0) && lreal;
    const size_t xbase = (size_t)(b0 + (col >> 2)) * Tt * In;
    float xr[5] = {0.f, 0.f, 0.f, 0.f, 0.f};
    // persistent fragments: dead lanes keep zeros forever (= LDS zeros)
    bf16x8 xhi, oh0, oh1, bh0, bh1;
    #pragma unroll
    for (int j = 0; j < 8; ++j) {
        xhi[j] = 0; oh0[j] = 0; oh1[j] = 0; bh0[j] = 0; bh1[j] = 0;
    }
    if (xmask) {   // load + split x(0) before the loop
        #pragma unroll
        for (int j = 0; j < In; ++j) xr[j] = x[xbase + j];
        #pragma unroll
        for (int j = 0; j < In; ++j) xhi[j] = f2bf_rne(xr[j]);
    }

    float c0 = 0.f;   // cell state for (b=kg, u=ub+col)

    __syncthreads();

    // ---- systolic main loop: 258 iterations, manually 2x unrolled ----
    #pragma unroll 1
    for (int t2 = 0; t2 < Tt + 2; t2 += 2) {
        STEP(t2,     roA, rbA_, wrA);   // reads parity 1, writes parity 0
        STEP(t2 + 1, roB, rbB_, wrB);   // reads parity 0, writes parity 1
    }

    // ---- final FC on h2(T-1) from the fp32 sidecar ----
    if (tid < TBr) {
        const int b = tid;
        float accf = b_fc[0];
        #pragma unroll 1
        for (int u = 0; u < Hh; ++u)
            accf = fmaf(h2f[b][u], w_fc[u], accf);
        out[b0 + b] = accf;
    }
}

extern "C" void kernel_launch(void* const* d_in, const int* in_sizes, int n_in,
                              void* d_out, int out_size, void* d_ws, size_t ws_size,
                              hipStream_t stream) {
    const float* x     = (const float*)d_in[0];
    const float* w_ih0 = (const float*)d_in[1];
    const float* w_hh0 = (const float*)d_in[2];
    const float* b_ih0 = (const float*)d_in[3];
    const float* b_hh0 = (const float*)d_in[4];
    const float* w_ih1 = (const float*)d_in[5];
    const float* w_hh1 = (const float*)d_in[6];
    const float* b_ih1 = (const float*)d_in[7];
    const float* b_hh1 = (const float*)d_in[8];
    const float* w_ih2 = (const float*)d_in[9];
    const float* w_hh2 = (const float*)d_in[10];
    const float* b_ih2 = (const float*)d_in[11];
    const float* b_hh2 = (const float*)d_in[12];
    const float* w_fc  = (const float*)d_in[13];
    const float* b_fc  = (const float*)d_in[14];
    float* out = (float*)d_out;

    lstm3_mfma<<<NB, NT, 0, stream>>>(x,
        w_ih0, w_hh0, b_ih0, b_hh0,
        w_ih1, w_hh1, b_ih1, b_hh1,
        w_ih2, w_hh2, b_ih2, b_hh2,
        w_fc, b_fc, out);
}